// Round 6
// baseline (4427.086 us; speedup 1.0000x reference)
//
#include <hip/hip_runtime.h>

#define S_LEN 128
#define BATCH 32
#define HID   512
#define GATES 2048      // 4*HID
#define VOCAB 32000
#define NROWS 4096      // S_LEN*BATCH
#define NWG   64        // persistent WGs
#define WROWS 32        // gate rows per WG

typedef short bf16x8 __attribute__((ext_vector_type(8)));
typedef float f32x4  __attribute__((ext_vector_type(4)));

__device__ __forceinline__ unsigned short f2bf(float f) {
    unsigned int u = __builtin_bit_cast(unsigned int, f);
    u += 0x7fffu + ((u >> 16) & 1u);            // RNE
    return (unsigned short)(u >> 16);
}
__device__ __forceinline__ float bf2f(unsigned short h) {
    unsigned int u = ((unsigned int)h) << 16;
    return __builtin_bit_cast(float, u);
}
__device__ __forceinline__ float sigmoidf_(float x) { return 1.0f / (1.0f + __expf(-x)); }

// ---- coherent (LLC-level, cross-XCD) memory ops: bypass non-coherent per-XCD L2 ----
__device__ __forceinline__ void st_coh_f32(void* p, float v) {
    asm volatile("global_store_dword %0, %1, off sc0 sc1" :: "v"(p), "v"(v) : "memory");
}
__device__ __forceinline__ void st_coh_u32(void* p, unsigned v) {
    asm volatile("global_store_dword %0, %1, off sc0 sc1" :: "v"(p), "v"(v) : "memory");
}
__device__ __forceinline__ void st_coh_u16(void* p, unsigned v) {
    asm volatile("global_store_short %0, %1, off sc0 sc1" :: "v"(p), "v"(v) : "memory");
}

// ---------------- embedding gather -> bf16 hi/lo pair ----------------
__global__ __launch_bounds__(256) void embed_k(const int* __restrict__ tokens,
                                               const float* __restrict__ emb,
                                               unsigned short* __restrict__ xhi,
                                               unsigned short* __restrict__ xlo) {
    int gid = blockIdx.x * 256 + threadIdx.x;   // NROWS*128 float4-groups
    int r = gid >> 7, e4 = gid & 127;
    int tok = tokens[r];
    float4 v = ((const float4*)(emb + (size_t)tok * HID))[e4];
    ushort4 hi, lo;
    hi.x = f2bf(v.x); lo.x = f2bf(v.x - bf2f(hi.x));
    hi.y = f2bf(v.y); lo.y = f2bf(v.y - bf2f(hi.y));
    hi.z = f2bf(v.z); lo.z = f2bf(v.z - bf2f(hi.z));
    hi.w = f2bf(v.w); lo.w = f2bf(v.w - bf2f(hi.w));
    ((ushort4*)(xhi + (size_t)r * HID))[e4] = hi;
    ((ushort4*)(xlo + (size_t)r * HID))[e4] = lo;
}

// ---------------- f32 -> bf16 hi(/lo) split ----------------
__global__ __launch_bounds__(256) void f32_split_k(const float* __restrict__ in,
                                                   unsigned short* __restrict__ hi,
                                                   unsigned short* __restrict__ lo, int n4) {
    int i = blockIdx.x * 256 + threadIdx.x;
    if (i >= n4) return;
    float4 v = ((const float4*)in)[i];
    ushort4 h, l;
    h.x = f2bf(v.x); l.x = f2bf(v.x - bf2f(h.x));
    h.y = f2bf(v.y); l.y = f2bf(v.y - bf2f(h.y));
    h.z = f2bf(v.z); l.z = f2bf(v.z - bf2f(h.z));
    h.w = f2bf(v.w); l.w = f2bf(v.w - bf2f(h.w));
    ((ushort4*)hi)[i] = h;
    if (lo) ((ushort4*)lo)[i] = l;
}

// ---------------- split-bf16 MFMA GEMM: C[M,N] = A[M,512] * W[N,512]^T (+bias) ----------------
template<int NPASS>
__global__ __launch_bounds__(256) void gemm_split(const unsigned short* __restrict__ Ahi,
                                                  const unsigned short* __restrict__ Alo,
                                                  const unsigned short* __restrict__ Whi,
                                                  const unsigned short* __restrict__ Wlo,
                                                  const float* __restrict__ bias,
                                                  float* __restrict__ C, int M, int N) {
    const int K = 512;
    __shared__ __align__(16) unsigned short As[128][72];   // +8 pad: 144B stride
    __shared__ __align__(16) unsigned short Bs[128][72];
    int tid = threadIdx.x;
    int n0 = blockIdx.x * 128, m0 = blockIdx.y * 128;
    int wave = tid >> 6, lane = tid & 63;
    int wm = (wave >> 1) * 64, wn = (wave & 1) * 64;
    int lr = lane & 15, kg = lane >> 4;
    f32x4 zero = {0.f, 0.f, 0.f, 0.f};
    f32x4 acc[4][4];
    for (int i = 0; i < 4; ++i)
        for (int j = 0; j < 4; ++j) acc[i][j] = zero;

    const unsigned short* Ap[3] = {Ahi, Ahi, Alo};
    const unsigned short* Wp[3] = {Whi, Wlo, Whi};

    #pragma unroll 1
    for (int p = 0; p < NPASS; ++p) {
        const unsigned short* A = Ap[p];
        const unsigned short* W = Wp[p];
        #pragma unroll 1
        for (int kt = 0; kt < K; kt += 64) {
            uint4 ar[4], br[4];
            #pragma unroll
            for (int q = 0; q < 4; ++q) {
                int c = q * 256 + tid, r = c >> 3, kc = c & 7;
                ar[q] = *(const uint4*)(A + (size_t)(m0 + r) * K + kt + kc * 8);
                br[q] = *(const uint4*)(W + (size_t)(n0 + r) * K + kt + kc * 8);
            }
            __syncthreads();
            #pragma unroll
            for (int q = 0; q < 4; ++q) {
                int c = q * 256 + tid, r = c >> 3, kc = c & 7;
                *(uint4*)&As[r][kc * 8] = ar[q];
                *(uint4*)&Bs[r][kc * 8] = br[q];
            }
            __syncthreads();
            #pragma unroll
            for (int kk = 0; kk < 2; ++kk) {
                bf16x8 af[4], bfr[4];
                #pragma unroll
                for (int i = 0; i < 4; ++i) af[i]  = *(const bf16x8*)&As[wm + i * 16 + lr][kk * 32 + kg * 8];
                #pragma unroll
                for (int j = 0; j < 4; ++j) bfr[j] = *(const bf16x8*)&Bs[wn + j * 16 + lr][kk * 32 + kg * 8];
                #pragma unroll
                for (int i = 0; i < 4; ++i)
                    #pragma unroll
                    for (int j = 0; j < 4; ++j)
                        acc[i][j] = __builtin_amdgcn_mfma_f32_16x16x32_bf16(af[i], bfr[j], acc[i][j], 0, 0, 0);
            }
        }
    }
    #pragma unroll
    for (int i = 0; i < 4; ++i) {
        int crow = m0 + wm + i * 16 + kg * 4;
        #pragma unroll
        for (int j = 0; j < 4; ++j) {
            int ccol = n0 + wn + j * 16 + lr;
            float bb = bias ? bias[ccol] : 0.0f;
            #pragma unroll
            for (int r = 0; r < 4; ++r)
                C[(size_t)(crow + r) * N + ccol] = acc[i][j][r] + bb;
        }
    }
}

// ---------------- row LayerNorm in-place: P[4096][2048], apply g,b ----------------
__global__ __launch_bounds__(256) void ln_rows_k(float* __restrict__ P,
                                                 const float* __restrict__ g,
                                                 const float* __restrict__ b) {
    int row = blockIdx.x, tid = threadIdx.x;
    float* p = P + (size_t)row * GATES;
    float4 v0 = ((const float4*)p)[tid];
    float4 v1 = ((const float4*)p)[tid + 256];
    float s  = v0.x + v0.y + v0.z + v0.w + v1.x + v1.y + v1.z + v1.w;
    float sq = v0.x*v0.x + v0.y*v0.y + v0.z*v0.z + v0.w*v0.w
             + v1.x*v1.x + v1.y*v1.y + v1.z*v1.z + v1.w*v1.w;
    __shared__ float rs[256], rq[256];
    rs[tid] = s; rq[tid] = sq; __syncthreads();
    for (int off = 128; off > 0; off >>= 1) {
        if (tid < off) { rs[tid] += rs[tid + off]; rq[tid] += rq[tid + off]; }
        __syncthreads();
    }
    float mean = rs[0] * (1.0f / GATES);
    float var  = rq[0] * (1.0f / GATES) - mean * mean;
    float inv  = rsqrtf(var + 1e-5f);
    float4 g0 = ((const float4*)g)[tid], g1 = ((const float4*)g)[tid + 256];
    float4 b0 = ((const float4*)b)[tid], b1 = ((const float4*)b)[tid + 256];
    float4 o0, o1;
    o0.x = (v0.x - mean) * inv * g0.x + b0.x;
    o0.y = (v0.y - mean) * inv * g0.y + b0.y;
    o0.z = (v0.z - mean) * inv * g0.z + b0.z;
    o0.w = (v0.w - mean) * inv * g0.w + b0.w;
    o1.x = (v1.x - mean) * inv * g1.x + b1.x;
    o1.y = (v1.y - mean) * inv * g1.y + b1.y;
    o1.z = (v1.z - mean) * inv * g1.z + b1.z;
    o1.w = (v1.w - mean) * inv * g1.w + b1.w;
    ((float4*)p)[tid] = o0;
    ((float4*)p)[tid + 256] = o1;
}

// ---------------- persistent LayerNorm-LSTM recurrence (one layer, all 128 steps)
// 64 WGs x 256 threads. WG w: phase A owns gate rows [w*32,w*32+32) as 3-term bf16 in LDS;
// phase B (w<32) owns batch element w (c-state in LDS). 6-pass split-MFMA z == f32 precision.
// Cross-WG payload via coherent sc0/sc1 ops; compact-flag barriers; no cache-wide fences.
__global__ __launch_bounds__(256, 1) void lstm_persist_k(
        const float* __restrict__ Whh,       // [2048][512] (layer slice, f32)
        const float* __restrict__ gh, const float* __restrict__ bh,
        const float* __restrict__ gc, const float* __restrict__ bc,
        const float* __restrict__ LNi,       // [4096][2048] precomputed LN(x@Wi^T)
        unsigned short* __restrict__ hHi,    // [32][512] 3-term bf16 h state (init 0)
        unsigned short* __restrict__ hMid,
        unsigned short* __restrict__ hLo,
        float* __restrict__ zbuf,            // [32][2048]
        unsigned* __restrict__ flagsA,       // [64] compact
        unsigned* __restrict__ flagsB,       // [32] compact
        unsigned short* __restrict__ seqHi,  // [4096][512]
        unsigned short* __restrict__ seqLo,  // nullable
        float* __restrict__ outH,            // [32][512] final h (f32)
        float* __restrict__ outC) {          // [32][512] final c (f32)
    __shared__ __align__(16) unsigned short Wlds[3][WROWS * HID];  // 96 KB
    __shared__ float ghs[GATES], bhs[GATES];                       // 16 KB
    __shared__ float gcs[HID], bcs[HID];                           // 4 KB
    __shared__ float c_lds[HID];                                   // 2 KB
    __shared__ float zred[4][2];
    __shared__ float credl[4][2];

    const int w = blockIdx.x;
    const int tid = threadIdx.x;
    const int wave = tid >> 6, lane = tid & 63;
    const int lr = lane & 15, kg = lane >> 4;
    const int mr = wave >> 1, nc = wave & 1;

    for (int u = tid; u < GATES; u += 256) { ghs[u] = gh[u]; bhs[u] = bh[u]; }
    for (int u = tid; u < HID;   u += 256) { gcs[u] = gc[u]; bcs[u] = bc[u]; c_lds[u] = 0.f; }

    // ---- stage Whh rows [w*32, w*32+32) -> 3-term bf16, XOR-swizzled 16B chunks ----
    #pragma unroll
    for (int i = 0; i < 8; ++i) {
        int chunk = tid + i * 256;            // 0..2047 : row r (0..31), 8-elem chunk c8 (0..63)
        int r = chunk >> 6, c8 = chunk & 63;
        const float* src = Whh + (size_t)(w * WROWS + r) * HID + c8 * 8;
        float4 v0 = *(const float4*)(src);
        float4 v1 = *(const float4*)(src + 4);
        float f[8] = {v0.x, v0.y, v0.z, v0.w, v1.x, v1.y, v1.z, v1.w};
        bf16x8 t0, t1, t2;
        #pragma unroll
        for (int e = 0; e < 8; ++e) {
            unsigned short h0 = f2bf(f[e]);
            float r1 = f[e] - bf2f(h0);
            unsigned short h1 = f2bf(r1);
            float r2 = r1 - bf2f(h1);
            t0[e] = (short)h0; t1[e] = (short)h1; t2[e] = (short)f2bf(r2);
        }
        int eoff = r * HID + ((c8 * 8) ^ ((r & 7) * 8));
        *(bf16x8*)&Wlds[0][eoff] = t0;
        *(bf16x8*)&Wlds[1][eoff] = t1;
        *(bf16x8*)&Wlds[2][eoff] = t2;
    }
    __syncthreads();

    const int arow = (mr * 16 + lr) * HID;
    const int wrow = (nc * 16 + lr) * HID;
    const int sw = (lr & 7) * 8;

    for (int t = 0; t < S_LEN; ++t) {
        const unsigned tagz = (unsigned)(t + 1);
        // ---- prefetch LNi row for phase B (plain loads, off critical path) ----
        float lrp[8];
        if (w < BATCH) {
            #pragma unroll
            for (int q = 0; q < 2; ++q)
                #pragma unroll
                for (int part = 0; part < 4; ++part) {
                    const void* p = LNi + (size_t)(t * BATCH + w) * GATES + (tid + q * 256 + part * 512);
                    asm volatile("global_load_dword %0, %1, off"
                                 : "=v"(lrp[q * 4 + part]) : "v"(p) : "memory");
                }
        }
        // ===== Phase A: z[b][w*32+j] = h @ W_slice^T, 6-pass 3-term, pipelined loads =====
        f32x4 zero = {0.f, 0.f, 0.f, 0.f};
        f32x4 acc[4] = {zero, zero, zero, zero};
        uint4 hA[16], hB[16];
#define ISSUE_H(DST, SRC)                                                          \
        { _Pragma("unroll")                                                        \
          for (int kk = 0; kk < 16; ++kk) {                                        \
              const void* p = (SRC) + arow + kk * 32 + kg * 8;                     \
              asm volatile("global_load_dwordx4 %0, %1, off sc0 sc1"               \
                           : "=v"(DST[kk]) : "v"(p) : "memory");                   \
          } }
#define MF(HARR, TERM)                                                             \
        { _Pragma("unroll")                                                        \
          for (int kk = 0; kk < 16; ++kk) {                                        \
              bf16x8 bv = *(const bf16x8*)&Wlds[TERM][wrow + ((kk * 32 + kg * 8) ^ sw)]; \
              bf16x8 av = __builtin_bit_cast(bf16x8, HARR[kk]);                    \
              acc[kk & 3] = __builtin_amdgcn_mfma_f32_16x16x32_bf16(av, bv, acc[kk & 3], 0, 0, 0); \
          } }
        ISSUE_H(hA, hHi)
        ISSUE_H(hB, hMid)
        asm volatile("s_waitcnt vmcnt(16)" ::: "memory");
        __builtin_amdgcn_sched_barrier(0);
        MF(hA, 0) MF(hA, 1) MF(hA, 2)
        ISSUE_H(hA, hLo)                       // reuse hA registers
        asm volatile("s_waitcnt vmcnt(16)" ::: "memory");
        __builtin_amdgcn_sched_barrier(0);
        MF(hB, 0) MF(hB, 1)
        asm volatile("s_waitcnt vmcnt(0)" ::: "memory");
        __builtin_amdgcn_sched_barrier(0);
        MF(hA, 0)
#undef ISSUE_H
#undef MF
        f32x4 a = acc[0] + acc[1] + acc[2] + acc[3];

        // z stores (coherent)
        #pragma unroll
        for (int r = 0; r < 4; ++r) {
            int b = mr * 16 + kg * 4 + r;
            int col = w * WROWS + nc * 16 + lr;
            st_coh_f32(&zbuf[b * GATES + col], a[r]);
        }

        // ---- barrier 1: z visible. All WGs produce; only phase-B WGs need to wait. ----
        asm volatile("s_waitcnt vmcnt(0)" ::: "memory");
        __syncthreads();
        if (tid == 0) st_coh_u32(flagsA + w, tagz);
        if (w < BATCH) {
            if (tid < 64) {
                const unsigned* fp = flagsA + tid;
                unsigned v;
                do {
                    asm volatile("global_load_dword %0, %1, off sc0 sc1\n\ts_waitcnt vmcnt(0)"
                                 : "=v"(v) : "v"(fp) : "memory");
                } while (__any(v < tagz));
            }
            __syncthreads();

            // ===== Phase B: batch element g = w =====
            const int g = w;
            const int row = t * BATCH + g;
            const float* zrow = zbuf + g * GATES;
            float zv[8];
            #pragma unroll
            for (int q = 0; q < 2; ++q)
                #pragma unroll
                for (int part = 0; part < 4; ++part) {
                    const void* p = &zrow[tid + q * 256 + part * 512];
                    asm volatile("global_load_dword %0, %1, off sc0 sc1"
                                 : "=v"(zv[q * 4 + part]) : "v"(p) : "memory");
                }
            asm volatile("s_waitcnt vmcnt(0)" ::: "memory");
            __builtin_amdgcn_sched_barrier(0);

            // LN stats over the 2048 z values this WG just loaded
            float s = 0.f, sq = 0.f;
            #pragma unroll
            for (int e = 0; e < 8; ++e) { s += zv[e]; sq += zv[e] * zv[e]; }
            #pragma unroll
            for (int m = 1; m < 64; m <<= 1) { s += __shfl_xor(s, m); sq += __shfl_xor(sq, m); }
            if (lane == 0) { zred[wave][0] = s; zred[wave][1] = sq; }
            __syncthreads();
            float zs = zred[0][0] + zred[1][0] + zred[2][0] + zred[3][0];
            float zq = zred[0][1] + zred[1][1] + zred[2][1] + zred[3][1];
            float mean = zs * (1.0f / GATES);
            float var  = zq * (1.0f / GATES) - mean * mean;
            float inv  = rsqrtf(var + 1e-5f);

            float cvals[2], ovals[2];
            float cs = 0.f, cq = 0.f;
            #pragma unroll
            for (int q = 0; q < 2; ++q) {
                int u = tid + q * 256;
                float gi_ = (zv[q*4+0] - mean) * inv * ghs[u       ] + bhs[u       ] + lrp[q*4+0];
                float gf_ = (zv[q*4+1] - mean) * inv * ghs[u + 512 ] + bhs[u + 512 ] + lrp[q*4+1];
                float gg_ = (zv[q*4+2] - mean) * inv * ghs[u + 1024] + bhs[u + 1024] + lrp[q*4+2];
                float go_ = (zv[q*4+3] - mean) * inv * ghs[u + 1536] + bhs[u + 1536] + lrp[q*4+3];
                float c = sigmoidf_(gf_) * c_lds[u] + sigmoidf_(gi_) * tanhf(gg_);
                c_lds[u] = c;
                cvals[q] = c; ovals[q] = go_;
                cs += c; cq += c * c;
            }
            #pragma unroll
            for (int m = 1; m < 64; m <<= 1) { cs += __shfl_xor(cs, m); cq += __shfl_xor(cq, m); }
            if (lane == 0) { credl[wave][0] = cs; credl[wave][1] = cq; }
            __syncthreads();
            float csum  = credl[0][0] + credl[1][0] + credl[2][0] + credl[3][0];
            float cqsum = credl[0][1] + credl[1][1] + credl[2][1] + credl[3][1];
            float meanc = csum * (1.0f / HID);
            float varc  = cqsum * (1.0f / HID) - meanc * meanc;
            float invc  = rsqrtf(varc + 1e-5f);
            #pragma unroll
            for (int q = 0; q < 2; ++q) {
                int u = tid + q * 256;
                float h = sigmoidf_(ovals[q]) * tanhf((cvals[q] - meanc) * invc * gcs[u] + bcs[u]);
                unsigned short h0 = f2bf(h);
                float r1 = h - bf2f(h0);
                unsigned short h1 = f2bf(r1);
                unsigned short h2 = f2bf(r1 - bf2f(h1));
                st_coh_u16(&hHi [g * HID + u], h0);
                st_coh_u16(&hMid[g * HID + u], h1);
                st_coh_u16(&hLo [g * HID + u], h2);
                seqHi[(size_t)row * HID + u] = h0;            // plain: consumed post-kernel
                if (seqLo) seqLo[(size_t)row * HID + u] = h1;
                if (t == S_LEN - 1) { outH[g * HID + u] = h; outC[g * HID + u] = cvals[q]; }
            }
            asm volatile("s_waitcnt vmcnt(0)" ::: "memory");
            __syncthreads();
            if (tid == 0) st_coh_u32(flagsB + w, tagz);
        }

        // ---- barrier 2: h visible for next step ----
        if (t < S_LEN - 1) {
            if (tid < 64) {
                const unsigned* fp = flagsB + (tid & 31);   // lanes 32-63 mirror 0-31
                unsigned v;
                do {
                    asm volatile("global_load_dword %0, %1, off sc0 sc1\n\ts_waitcnt vmcnt(0)"
                                 : "=v"(v) : "v"(fp) : "memory");
                } while (__any(v < tagz));
            }
            __syncthreads();
        }
    }
}

// ---------------- in-place log-softmax over V, per row ----------------
__global__ __launch_bounds__(256) void logsoftmax_k(float* __restrict__ out) {
    int row = blockIdx.x, tid = threadIdx.x;
    float* p = out + (size_t)row * VOCAB;
    const float4* p4 = (const float4*)p;
    float m = -3.4e38f, s = 0.f;
    for (int j = tid; j < VOCAB / 4; j += 256) {
        float4 v = p4[j];
        float xs[4] = {v.x, v.y, v.z, v.w};
        #pragma unroll
        for (int e = 0; e < 4; ++e) {
            float x = xs[e];
            if (x > m) { s *= __expf(m - x); m = x; }
            s += __expf(x - m);
        }
    }
    __shared__ float rm[256], rv[256];
    rm[tid] = m; rv[tid] = s; __syncthreads();
    for (int off = 128; off > 0; off >>= 1) {
        if (tid < off) {
            float ma = rm[tid], mb = rm[tid + off];
            float M = fmaxf(ma, mb);
            rv[tid] = rv[tid] * __expf(ma - M) + rv[tid + off] * __expf(mb - M);
            rm[tid] = M;
        }
        __syncthreads();
    }
    float logZ = rm[0] + __logf(rv[0]);
    for (int j = tid; j < VOCAB / 4; j += 256) {
        float4 v = p4[j];
        v.x -= logZ; v.y -= logZ; v.z -= logZ; v.w -= logZ;
        ((float4*)p)[j] = v;
    }
}

extern "C" void kernel_launch(void* const* d_in, const int* in_sizes, int n_in,
                              void* d_out, int out_size, void* d_ws, size_t ws_size,
                              hipStream_t stream) {
    const int*   tokens = (const int*)d_in[0];
    const float* emb    = (const float*)d_in[1];
    const float* W_ih   = (const float*)d_in[2];
    const float* W_hh   = (const float*)d_in[3];
    const float* g_ih   = (const float*)d_in[4];
    const float* b_ih   = (const float*)d_in[5];
    const float* g_hh   = (const float*)d_in[6];
    const float* b_hh   = (const float*)d_in[7];
    const float* g_c    = (const float*)d_in[8];
    const float* b_c    = (const float*)d_in[9];
    const float* W_fc   = (const float*)d_in[10];
    const float* b_fc   = (const float*)d_in[11];
    float* out = (float*)d_out;

    char* ws = (char*)d_ws;
    unsigned short* XembHi  = (unsigned short*)(ws + 0);               //  4 MB
    unsigned short* XembLo  = (unsigned short*)(ws + ( 4ull << 20));   //  4 MB
    unsigned short* hseq0Hi = (unsigned short*)(ws + ( 8ull << 20));   //  4 MB
    unsigned short* hseq0Lo = (unsigned short*)(ws + (12ull << 20));   //  4 MB
    unsigned short* hseq1Hi = (unsigned short*)(ws + (16ull << 20));   //  4 MB
    unsigned short* WihHi   = (unsigned short*)(ws + (20ull << 20));   //  2 MB
    unsigned short* WihLo   = (unsigned short*)(ws + (22ull << 20));   //  2 MB
    unsigned short* WfcHi   = (unsigned short*)(ws + (24ull << 20));   // 32.8 MB
    float*          P       = (float*)(ws + (58ull << 20));            // 32 MB
    char*           xtra    = ws + (90ull << 20);
    float*          zbuf    = (float*)(xtra);                                   // 256 KB
    unsigned short* hHi     = (unsigned short*)(xtra + 0x40000);                // 32 KB
    unsigned short* hMid    = (unsigned short*)(xtra + 0x48000);                // 32 KB
    unsigned short* hLo     = (unsigned short*)(xtra + 0x50000);                // 32 KB
    unsigned*       flagsA  = (unsigned*)(xtra + 0x58000);                      // 256 B
    unsigned*       flagsB  = (unsigned*)(xtra + 0x58100);                      // 128 B

    float* tail = out + (size_t)NROWS * VOCAB;   // h_n [2][32][512] then c_n [2][32][512]

    embed_k<<<2048, 256, 0, stream>>>(tokens, emb, XembHi, XembLo);

    const unsigned short* xhi[2] = {XembHi, hseq0Hi};
    const unsigned short* xlo[2] = {XembLo, hseq0Lo};
    unsigned short* shi[2] = {hseq0Hi, hseq1Hi};
    unsigned short* slo[2] = {hseq0Lo, nullptr};

    for (int l = 0; l < 2; ++l) {
        f32_split_k<<<1024, 256, 0, stream>>>(W_ih + (size_t)l * GATES * HID, WihHi, WihLo, GATES * HID / 4);
        gemm_split<3><<<dim3(GATES / 128, NROWS / 128), 256, 0, stream>>>(
            xhi[l], xlo[l], WihHi, WihLo, nullptr, P, NROWS, GATES);
        ln_rows_k<<<NROWS, 256, 0, stream>>>(P, g_ih + l * GATES, b_ih + l * GATES);
        hipMemsetAsync(hHi,  0, BATCH * HID * sizeof(unsigned short), stream);
        hipMemsetAsync(hMid, 0, BATCH * HID * sizeof(unsigned short), stream);
        hipMemsetAsync(hLo,  0, BATCH * HID * sizeof(unsigned short), stream);
        hipMemsetAsync(flagsA, 0, 512, stream);   // covers flagsA + flagsB
        lstm_persist_k<<<NWG, 256, 0, stream>>>(
            W_hh + (size_t)l * GATES * HID,
            g_hh + l * GATES, b_hh + l * GATES,
            g_c + l * HID, b_c + l * HID,
            P, hHi, hMid, hLo, zbuf, flagsA, flagsB,
            shi[l], slo[l],
            tail + l * BATCH * HID,
            tail + 2 * BATCH * HID + l * BATCH * HID);
    }

    f32_split_k<<<16000, 256, 0, stream>>>(W_fc, WfcHi, nullptr, VOCAB * HID / 4);
    gemm_split<1><<<dim3(VOCAB / 128, NROWS / 128), 256, 0, stream>>>(
        hseq1Hi, nullptr, WfcHi, nullptr, b_fc, out, NROWS, VOCAB);
    logsoftmax_k<<<NROWS, 256, 0, stream>>>(out);
}

// Round 10
// 4399.434 us; speedup vs baseline: 1.0063x; 1.0063x over previous
//
#include <hip/hip_runtime.h>

#define S_LEN 128
#define BATCH 32
#define HID   512
#define GATES 2048      // 4*HID
#define VOCAB 32000
#define NROWS 4096      // S_LEN*BATCH
#define NWG   64        // persistent WGs
#define WROWS 32        // gate rows per WG

typedef short bf16x8 __attribute__((ext_vector_type(8)));
typedef float f32x4  __attribute__((ext_vector_type(4)));

__device__ __forceinline__ unsigned short f2bf(float f) {
    unsigned int u = __builtin_bit_cast(unsigned int, f);
    u += 0x7fffu + ((u >> 16) & 1u);            // RNE
    return (unsigned short)(u >> 16);
}
__device__ __forceinline__ float bf2f(unsigned short h) {
    unsigned int u = ((unsigned int)h) << 16;
    return __builtin_bit_cast(float, u);
}
__device__ __forceinline__ float sigmoidf_(float x) { return 1.0f / (1.0f + __expf(-x)); }

// ---- coherent (LLC-level, cross-XCD) memory ops: bypass non-coherent per-XCD L2 ----
__device__ __forceinline__ void st_coh_f32(void* p, float v) {
    asm volatile("global_store_dword %0, %1, off sc0 sc1" :: "v"(p), "v"(v) : "memory");
}
__device__ __forceinline__ void st_coh_u32(void* p, unsigned v) {
    asm volatile("global_store_dword %0, %1, off sc0 sc1" :: "v"(p), "v"(v) : "memory");
}
__device__ __forceinline__ void st_coh_u16(void* p, unsigned v) {
    asm volatile("global_store_short %0, %1, off sc0 sc1" :: "v"(p), "v"(v) : "memory");
}

// ---------------- embedding gather -> bf16 hi/lo pair ----------------
__global__ __launch_bounds__(256) void embed_k(const int* __restrict__ tokens,
                                               const float* __restrict__ emb,
                                               unsigned short* __restrict__ xhi,
                                               unsigned short* __restrict__ xlo) {
    int gid = blockIdx.x * 256 + threadIdx.x;   // NROWS*128 float4-groups
    int r = gid >> 7, e4 = gid & 127;
    int tok = tokens[r];
    float4 v = ((const float4*)(emb + (size_t)tok * HID))[e4];
    ushort4 hi, lo;
    hi.x = f2bf(v.x); lo.x = f2bf(v.x - bf2f(hi.x));
    hi.y = f2bf(v.y); lo.y = f2bf(v.y - bf2f(hi.y));
    hi.z = f2bf(v.z); lo.z = f2bf(v.z - bf2f(hi.z));
    hi.w = f2bf(v.w); lo.w = f2bf(v.w - bf2f(hi.w));
    ((ushort4*)(xhi + (size_t)r * HID))[e4] = hi;
    ((ushort4*)(xlo + (size_t)r * HID))[e4] = lo;
}

// ---------------- f32 -> bf16 hi(/lo) split ----------------
__global__ __launch_bounds__(256) void f32_split_k(const float* __restrict__ in,
                                                   unsigned short* __restrict__ hi,
                                                   unsigned short* __restrict__ lo, int n4) {
    int i = blockIdx.x * 256 + threadIdx.x;
    if (i >= n4) return;
    float4 v = ((const float4*)in)[i];
    ushort4 h, l;
    h.x = f2bf(v.x); l.x = f2bf(v.x - bf2f(h.x));
    h.y = f2bf(v.y); l.y = f2bf(v.y - bf2f(h.y));
    h.z = f2bf(v.z); l.z = f2bf(v.z - bf2f(h.z));
    h.w = f2bf(v.w); l.w = f2bf(v.w - bf2f(h.w));
    ((ushort4*)hi)[i] = h;
    if (lo) ((ushort4*)lo)[i] = l;
}

// ---------------- split-bf16 MFMA GEMM: C[M,N] = A[M,512] * W[N,512]^T (+bias) ----------------
template<int NPASS>
__global__ __launch_bounds__(256) void gemm_split(const unsigned short* __restrict__ Ahi,
                                                  const unsigned short* __restrict__ Alo,
                                                  const unsigned short* __restrict__ Whi,
                                                  const unsigned short* __restrict__ Wlo,
                                                  const float* __restrict__ bias,
                                                  float* __restrict__ C, int M, int N) {
    const int K = 512;
    __shared__ __align__(16) unsigned short As[128][72];   // +8 pad: 144B stride
    __shared__ __align__(16) unsigned short Bs[128][72];
    int tid = threadIdx.x;
    int n0 = blockIdx.x * 128, m0 = blockIdx.y * 128;
    int wave = tid >> 6, lane = tid & 63;
    int wm = (wave >> 1) * 64, wn = (wave & 1) * 64;
    int lr = lane & 15, kg = lane >> 4;
    f32x4 zero = {0.f, 0.f, 0.f, 0.f};
    f32x4 acc[4][4];
    for (int i = 0; i < 4; ++i)
        for (int j = 0; j < 4; ++j) acc[i][j] = zero;

    const unsigned short* Ap[3] = {Ahi, Ahi, Alo};
    const unsigned short* Wp[3] = {Whi, Wlo, Whi};

    #pragma unroll 1
    for (int p = 0; p < NPASS; ++p) {
        const unsigned short* A = Ap[p];
        const unsigned short* W = Wp[p];
        #pragma unroll 1
        for (int kt = 0; kt < K; kt += 64) {
            uint4 ar[4], br[4];
            #pragma unroll
            for (int q = 0; q < 4; ++q) {
                int c = q * 256 + tid, r = c >> 3, kc = c & 7;
                ar[q] = *(const uint4*)(A + (size_t)(m0 + r) * K + kt + kc * 8);
                br[q] = *(const uint4*)(W + (size_t)(n0 + r) * K + kt + kc * 8);
            }
            __syncthreads();
            #pragma unroll
            for (int q = 0; q < 4; ++q) {
                int c = q * 256 + tid, r = c >> 3, kc = c & 7;
                *(uint4*)&As[r][kc * 8] = ar[q];
                *(uint4*)&Bs[r][kc * 8] = br[q];
            }
            __syncthreads();
            #pragma unroll
            for (int kk = 0; kk < 2; ++kk) {
                bf16x8 af[4], bfr[4];
                #pragma unroll
                for (int i = 0; i < 4; ++i) af[i]  = *(const bf16x8*)&As[wm + i * 16 + lr][kk * 32 + kg * 8];
                #pragma unroll
                for (int j = 0; j < 4; ++j) bfr[j] = *(const bf16x8*)&Bs[wn + j * 16 + lr][kk * 32 + kg * 8];
                #pragma unroll
                for (int i = 0; i < 4; ++i)
                    #pragma unroll
                    for (int j = 0; j < 4; ++j)
                        acc[i][j] = __builtin_amdgcn_mfma_f32_16x16x32_bf16(af[i], bfr[j], acc[i][j], 0, 0, 0);
            }
        }
    }
    #pragma unroll
    for (int i = 0; i < 4; ++i) {
        int crow = m0 + wm + i * 16 + kg * 4;
        #pragma unroll
        for (int j = 0; j < 4; ++j) {
            int ccol = n0 + wn + j * 16 + lr;
            float bb = bias ? bias[ccol] : 0.0f;
            #pragma unroll
            for (int r = 0; r < 4; ++r)
                C[(size_t)(crow + r) * N + ccol] = acc[i][j][r] + bb;
        }
    }
}

// ---------------- row LayerNorm in-place: P[4096][2048], apply g,b ----------------
__global__ __launch_bounds__(256) void ln_rows_k(float* __restrict__ P,
                                                 const float* __restrict__ g,
                                                 const float* __restrict__ b) {
    int row = blockIdx.x, tid = threadIdx.x;
    float* p = P + (size_t)row * GATES;
    float4 v0 = ((const float4*)p)[tid];
    float4 v1 = ((const float4*)p)[tid + 256];
    float s  = v0.x + v0.y + v0.z + v0.w + v1.x + v1.y + v1.z + v1.w;
    float sq = v0.x*v0.x + v0.y*v0.y + v0.z*v0.z + v0.w*v0.w
             + v1.x*v1.x + v1.y*v1.y + v1.z*v1.z + v1.w*v1.w;
    __shared__ float rs[256], rq[256];
    rs[tid] = s; rq[tid] = sq; __syncthreads();
    for (int off = 128; off > 0; off >>= 1) {
        if (tid < off) { rs[tid] += rs[tid + off]; rq[tid] += rq[tid + off]; }
        __syncthreads();
    }
    float mean = rs[0] * (1.0f / GATES);
    float var  = rq[0] * (1.0f / GATES) - mean * mean;
    float inv  = rsqrtf(var + 1e-5f);
    float4 g0 = ((const float4*)g)[tid], g1 = ((const float4*)g)[tid + 256];
    float4 b0 = ((const float4*)b)[tid], b1 = ((const float4*)b)[tid + 256];
    float4 o0, o1;
    o0.x = (v0.x - mean) * inv * g0.x + b0.x;
    o0.y = (v0.y - mean) * inv * g0.y + b0.y;
    o0.z = (v0.z - mean) * inv * g0.z + b0.z;
    o0.w = (v0.w - mean) * inv * g0.w + b0.w;
    o1.x = (v1.x - mean) * inv * g1.x + b1.x;
    o1.y = (v1.y - mean) * inv * g1.y + b1.y;
    o1.z = (v1.z - mean) * inv * g1.z + b1.z;
    o1.w = (v1.w - mean) * inv * g1.w + b1.w;
    ((float4*)p)[tid] = o0;
    ((float4*)p)[tid + 256] = o1;
}

// ---------------- persistent LayerNorm-LSTM recurrence (one layer, all 128 steps)
// 64 WGs x 256 threads. WG w: phase A owns gate rows [w*32,w*32+32) as 3-term bf16 in LDS;
// phase B (w<32) owns batch element w (c-state in LDS). 6-pass split-MFMA z == f32 precision.
// Cross-WG payload via coherent sc0/sc1 ops; compact-flag barriers; no cache-wide fences.
__global__ __launch_bounds__(256, 1) void lstm_persist_k(
        const float* __restrict__ Whh,       // [2048][512] (layer slice, f32)
        const float* __restrict__ gh, const float* __restrict__ bh,
        const float* __restrict__ gc, const float* __restrict__ bc,
        const float* __restrict__ LNi,       // [4096][2048] precomputed LN(x@Wi^T)
        unsigned short* __restrict__ hHi,    // [32][512] 3-term bf16 h state (init 0)
        unsigned short* __restrict__ hMid,
        unsigned short* __restrict__ hLo,
        float* __restrict__ zbuf,            // [32][2048]
        unsigned* __restrict__ flagsA,       // [64] compact
        unsigned* __restrict__ flagsB,       // [32] compact
        unsigned short* __restrict__ seqHi,  // [4096][512]
        unsigned short* __restrict__ seqLo,  // nullable
        float* __restrict__ outH,            // [32][512] final h (f32)
        float* __restrict__ outC) {          // [32][512] final c (f32)
    __shared__ __align__(16) unsigned short Wlds[3][WROWS * HID];  // 96 KB
    __shared__ float ghs[GATES], bhs[GATES];                       // 16 KB
    __shared__ float gcs[HID], bcs[HID];                           // 4 KB
    __shared__ float c_lds[HID];                                   // 2 KB
    __shared__ float zred[4][2];
    __shared__ float credl[4][2];

    const int w = blockIdx.x;
    const int tid = threadIdx.x;
    const int wave = tid >> 6, lane = tid & 63;
    const int lr = lane & 15, kg = lane >> 4;
    const int mr = wave >> 1, nc = wave & 1;

    for (int u = tid; u < GATES; u += 256) { ghs[u] = gh[u]; bhs[u] = bh[u]; }
    for (int u = tid; u < HID;   u += 256) { gcs[u] = gc[u]; bcs[u] = bc[u]; c_lds[u] = 0.f; }

    // ---- stage Whh rows [w*32, w*32+32) -> 3-term bf16, XOR-swizzled 16B chunks ----
    #pragma unroll
    for (int i = 0; i < 8; ++i) {
        int chunk = tid + i * 256;            // 0..2047 : row r (0..31), 8-elem chunk c8 (0..63)
        int r = chunk >> 6, c8 = chunk & 63;
        const float* src = Whh + (size_t)(w * WROWS + r) * HID + c8 * 8;
        float4 v0 = *(const float4*)(src);
        float4 v1 = *(const float4*)(src + 4);
        float f[8] = {v0.x, v0.y, v0.z, v0.w, v1.x, v1.y, v1.z, v1.w};
        bf16x8 t0, t1, t2;
        #pragma unroll
        for (int e = 0; e < 8; ++e) {
            unsigned short h0 = f2bf(f[e]);
            float r1 = f[e] - bf2f(h0);
            unsigned short h1 = f2bf(r1);
            float r2 = r1 - bf2f(h1);
            t0[e] = (short)h0; t1[e] = (short)h1; t2[e] = (short)f2bf(r2);
        }
        int eoff = r * HID + ((c8 * 8) ^ ((r & 7) * 8));
        *(bf16x8*)&Wlds[0][eoff] = t0;
        *(bf16x8*)&Wlds[1][eoff] = t1;
        *(bf16x8*)&Wlds[2][eoff] = t2;
    }
    __syncthreads();

    const int arow = (mr * 16 + lr) * HID;
    const int wrow = (nc * 16 + lr) * HID;
    const int sw = (lr & 7) * 8;

    for (int t = 0; t < S_LEN; ++t) {
        const unsigned tagz = (unsigned)(t + 1);
        // ---- prefetch LNi row for phase B (plain loads, off critical path) ----
        float lrp[8];
        if (w < BATCH) {
            #pragma unroll
            for (int q = 0; q < 2; ++q)
                #pragma unroll
                for (int part = 0; part < 4; ++part) {
                    const void* p = LNi + (size_t)(t * BATCH + w) * GATES + (tid + q * 256 + part * 512);
                    asm volatile("global_load_dword %0, %1, off"
                                 : "=v"(lrp[q * 4 + part]) : "v"(p) : "memory");
                }
        }
        // ===== Phase A: z[b][w*32+j] = h @ W_slice^T, 6-pass 3-term, pipelined loads =====
        f32x4 zero = {0.f, 0.f, 0.f, 0.f};
        f32x4 acc[4] = {zero, zero, zero, zero};
        uint4 hA[16], hB[16];
#define ISSUE_H(DST, SRC)                                                          \
        { _Pragma("unroll")                                                        \
          for (int kk = 0; kk < 16; ++kk) {                                        \
              const void* p = (SRC) + arow + kk * 32 + kg * 8;                     \
              asm volatile("global_load_dwordx4 %0, %1, off sc0 sc1"               \
                           : "=v"(DST[kk]) : "v"(p) : "memory");                   \
          } }
#define MF(HARR, TERM)                                                             \
        { _Pragma("unroll")                                                        \
          for (int kk = 0; kk < 16; ++kk) {                                        \
              bf16x8 bv = *(const bf16x8*)&Wlds[TERM][wrow + ((kk * 32 + kg * 8) ^ sw)]; \
              bf16x8 av = __builtin_bit_cast(bf16x8, HARR[kk]);                    \
              acc[kk & 3] = __builtin_amdgcn_mfma_f32_16x16x32_bf16(av, bv, acc[kk & 3], 0, 0, 0); \
          } }
        ISSUE_H(hA, hHi)
        ISSUE_H(hB, hMid)
        asm volatile("s_waitcnt vmcnt(16)" ::: "memory");
        __builtin_amdgcn_sched_barrier(0);
        MF(hA, 0) MF(hA, 1) MF(hA, 2)
        ISSUE_H(hA, hLo)                       // reuse hA registers
        asm volatile("s_waitcnt vmcnt(16)" ::: "memory");
        __builtin_amdgcn_sched_barrier(0);
        MF(hB, 0) MF(hB, 1)
        asm volatile("s_waitcnt vmcnt(0)" ::: "memory");
        __builtin_amdgcn_sched_barrier(0);
        MF(hA, 0)
#undef ISSUE_H
#undef MF
        f32x4 a = acc[0] + acc[1] + acc[2] + acc[3];

        // z stores (coherent)
        #pragma unroll
        for (int r = 0; r < 4; ++r) {
            int b = mr * 16 + kg * 4 + r;
            int col = w * WROWS + nc * 16 + lr;
            st_coh_f32(&zbuf[b * GATES + col], a[r]);
        }

        // ---- barrier 1: z visible. All WGs produce; only phase-B WGs need to wait. ----
        asm volatile("s_waitcnt vmcnt(0)" ::: "memory");
        __syncthreads();
        if (tid == 0) st_coh_u32(flagsA + w, tagz);
        if (w < BATCH) {
            if (tid < 64) {
                const unsigned* fp = flagsA + tid;
                unsigned v;
                do {
                    asm volatile("global_load_dword %0, %1, off sc0 sc1\n\ts_waitcnt vmcnt(0)"
                                 : "=v"(v) : "v"(fp) : "memory");
                } while (__any(v < tagz));
            }
            __syncthreads();

            // ===== Phase B: batch element g = w =====
            const int g = w;
            const int row = t * BATCH + g;
            const float* zrow = zbuf + g * GATES;
            float zv[8];
            #pragma unroll
            for (int q = 0; q < 2; ++q)
                #pragma unroll
                for (int part = 0; part < 4; ++part) {
                    const void* p = &zrow[tid + q * 256 + part * 512];
                    asm volatile("global_load_dword %0, %1, off sc0 sc1"
                                 : "=v"(zv[q * 4 + part]) : "v"(p) : "memory");
                }
            asm volatile("s_waitcnt vmcnt(0)" ::: "memory");
            __builtin_amdgcn_sched_barrier(0);

            // LN stats over the 2048 z values this WG just loaded
            float s = 0.f, sq = 0.f;
            #pragma unroll
            for (int e = 0; e < 8; ++e) { s += zv[e]; sq += zv[e] * zv[e]; }
            #pragma unroll
            for (int m = 1; m < 64; m <<= 1) { s += __shfl_xor(s, m); sq += __shfl_xor(sq, m); }
            if (lane == 0) { zred[wave][0] = s; zred[wave][1] = sq; }
            __syncthreads();
            float zs = zred[0][0] + zred[1][0] + zred[2][0] + zred[3][0];
            float zq = zred[0][1] + zred[1][1] + zred[2][1] + zred[3][1];
            float mean = zs * (1.0f / GATES);
            float var  = zq * (1.0f / GATES) - mean * mean;
            float inv  = rsqrtf(var + 1e-5f);

            float cvals[2], ovals[2];
            float cs = 0.f, cq = 0.f;
            #pragma unroll
            for (int q = 0; q < 2; ++q) {
                int u = tid + q * 256;
                float gi_ = (zv[q*4+0] - mean) * inv * ghs[u       ] + bhs[u       ] + lrp[q*4+0];
                float gf_ = (zv[q*4+1] - mean) * inv * ghs[u + 512 ] + bhs[u + 512 ] + lrp[q*4+1];
                float gg_ = (zv[q*4+2] - mean) * inv * ghs[u + 1024] + bhs[u + 1024] + lrp[q*4+2];
                float go_ = (zv[q*4+3] - mean) * inv * ghs[u + 1536] + bhs[u + 1536] + lrp[q*4+3];
                float c = sigmoidf_(gf_) * c_lds[u] + sigmoidf_(gi_) * tanhf(gg_);
                c_lds[u] = c;
                cvals[q] = c; ovals[q] = go_;
                cs += c; cq += c * c;
            }
            #pragma unroll
            for (int m = 1; m < 64; m <<= 1) { cs += __shfl_xor(cs, m); cq += __shfl_xor(cq, m); }
            if (lane == 0) { credl[wave][0] = cs; credl[wave][1] = cq; }
            __syncthreads();
            float csum  = credl[0][0] + credl[1][0] + credl[2][0] + credl[3][0];
            float cqsum = credl[0][1] + credl[1][1] + credl[2][1] + credl[3][1];
            float meanc = csum * (1.0f / HID);
            float varc  = cqsum * (1.0f / HID) - meanc * meanc;
            float invc  = rsqrtf(varc + 1e-5f);
            #pragma unroll
            for (int q = 0; q < 2; ++q) {
                int u = tid + q * 256;
                float h = sigmoidf_(ovals[q]) * tanhf((cvals[q] - meanc) * invc * gcs[u] + bcs[u]);
                unsigned short h0 = f2bf(h);
                float r1 = h - bf2f(h0);
                unsigned short h1 = f2bf(r1);
                unsigned short h2 = f2bf(r1 - bf2f(h1));
                st_coh_u16(&hHi [g * HID + u], h0);
                st_coh_u16(&hMid[g * HID + u], h1);
                st_coh_u16(&hLo [g * HID + u], h2);
                seqHi[(size_t)row * HID + u] = h0;            // plain: consumed post-kernel
                if (seqLo) seqLo[(size_t)row * HID + u] = h1;
                if (t == S_LEN - 1) { outH[g * HID + u] = h; outC[g * HID + u] = cvals[q]; }
            }
            asm volatile("s_waitcnt vmcnt(0)" ::: "memory");
            __syncthreads();
            if (tid == 0) st_coh_u32(flagsB + w, tagz);
        }

        // ---- barrier 2: h visible for next step ----
        if (t < S_LEN - 1) {
            if (tid < 64) {
                const unsigned* fp = flagsB + (tid & 31);   // lanes 32-63 mirror 0-31
                unsigned v;
                do {
                    asm volatile("global_load_dword %0, %1, off sc0 sc1\n\ts_waitcnt vmcnt(0)"
                                 : "=v"(v) : "v"(fp) : "memory");
                } while (__any(v < tagz));
            }
            __syncthreads();
        }
    }
}

// ---------------- in-place log-softmax over V, per row: LDS-staged (1 read + 1 write) ----------------
__global__ __launch_bounds__(512, 1) void logsoftmax_k(float* __restrict__ out) {
    __shared__ __align__(16) float row_lds[VOCAB];   // 125 KB
    __shared__ float rm[512], rv[512];
    int row = blockIdx.x, tid = threadIdx.x;
    float* p = out + (size_t)row * VOCAB;
    const float4* p4 = (const float4*)p;
    float m = -3.4e38f, s = 0.f;
    for (int j = tid; j < VOCAB / 4; j += 512) {
        float4 v = p4[j];
        *(float4*)&row_lds[j * 4] = v;               // stage while scanning
        float xs[4] = {v.x, v.y, v.z, v.w};
        #pragma unroll
        for (int e = 0; e < 4; ++e) {
            float x = xs[e];
            if (x > m) { s *= __expf(m - x); m = x; }
            s += __expf(x - m);
        }
    }
    rm[tid] = m; rv[tid] = s; __syncthreads();
    for (int off = 256; off > 0; off >>= 1) {
        if (tid < off) {
            float ma = rm[tid], mb = rm[tid + off];
            float M = fmaxf(ma, mb);
            rv[tid] = rv[tid] * __expf(ma - M) + rv[tid + off] * __expf(mb - M);
            rm[tid] = M;
        }
        __syncthreads();
    }
    float logZ = rm[0] + __logf(rv[0]);
    for (int j = tid; j < VOCAB / 4; j += 512) {
        float4 v = *(const float4*)&row_lds[j * 4];
        v.x -= logZ; v.y -= logZ; v.z -= logZ; v.w -= logZ;
        ((float4*)p)[j] = v;
    }
}

extern "C" void kernel_launch(void* const* d_in, const int* in_sizes, int n_in,
                              void* d_out, int out_size, void* d_ws, size_t ws_size,
                              hipStream_t stream) {
    const int*   tokens = (const int*)d_in[0];
    const float* emb    = (const float*)d_in[1];
    const float* W_ih   = (const float*)d_in[2];
    const float* W_hh   = (const float*)d_in[3];
    const float* g_ih   = (const float*)d_in[4];
    const float* b_ih   = (const float*)d_in[5];
    const float* g_hh   = (const float*)d_in[6];
    const float* b_hh   = (const float*)d_in[7];
    const float* g_c    = (const float*)d_in[8];
    const float* b_c    = (const float*)d_in[9];
    const float* W_fc   = (const float*)d_in[10];
    const float* b_fc   = (const float*)d_in[11];
    float* out = (float*)d_out;

    char* ws = (char*)d_ws;
    unsigned short* XembHi  = (unsigned short*)(ws + 0);               //  4 MB
    unsigned short* XembLo  = (unsigned short*)(ws + ( 4ull << 20));   //  4 MB
    unsigned short* hseq0Hi = (unsigned short*)(ws + ( 8ull << 20));   //  4 MB
    unsigned short* hseq0Lo = (unsigned short*)(ws + (12ull << 20));   //  4 MB
    unsigned short* hseq1Hi = (unsigned short*)(ws + (16ull << 20));   //  4 MB
    unsigned short* WihHi   = (unsigned short*)(ws + (20ull << 20));   //  2 MB
    unsigned short* WihLo   = (unsigned short*)(ws + (22ull << 20));   //  2 MB
    unsigned short* WfcHi   = (unsigned short*)(ws + (24ull << 20));   // 32.8 MB
    float*          P       = (float*)(ws + (58ull << 20));            // 32 MB
    char*           xtra    = ws + (90ull << 20);
    float*          zbuf    = (float*)(xtra);                                   // 256 KB
    unsigned short* hHi     = (unsigned short*)(xtra + 0x40000);                // 32 KB
    unsigned short* hMid    = (unsigned short*)(xtra + 0x48000);                // 32 KB
    unsigned short* hLo     = (unsigned short*)(xtra + 0x50000);                // 32 KB
    unsigned*       flagsA  = (unsigned*)(xtra + 0x58000);                      // 256 B
    unsigned*       flagsB  = (unsigned*)(xtra + 0x58100);                      // 128 B

    float* tail = out + (size_t)NROWS * VOCAB;   // h_n [2][32][512] then c_n [2][32][512]

    embed_k<<<2048, 256, 0, stream>>>(tokens, emb, XembHi, XembLo);

    const unsigned short* xhi[2] = {XembHi, hseq0Hi};
    const unsigned short* xlo[2] = {XembLo, hseq0Lo};
    unsigned short* shi[2] = {hseq0Hi, hseq1Hi};
    unsigned short* slo[2] = {hseq0Lo, nullptr};

    for (int l = 0; l < 2; ++l) {
        f32_split_k<<<1024, 256, 0, stream>>>(W_ih + (size_t)l * GATES * HID, WihHi, WihLo, GATES * HID / 4);
        gemm_split<3><<<dim3(GATES / 128, NROWS / 128), 256, 0, stream>>>(
            xhi[l], xlo[l], WihHi, WihLo, nullptr, P, NROWS, GATES);
        ln_rows_k<<<NROWS, 256, 0, stream>>>(P, g_ih + l * GATES, b_ih + l * GATES);
        hipMemsetAsync(hHi,  0, BATCH * HID * sizeof(unsigned short), stream);
        hipMemsetAsync(hMid, 0, BATCH * HID * sizeof(unsigned short), stream);
        hipMemsetAsync(hLo,  0, BATCH * HID * sizeof(unsigned short), stream);
        hipMemsetAsync(flagsA, 0, 512, stream);   // covers flagsA + flagsB
        lstm_persist_k<<<NWG, 256, 0, stream>>>(
            W_hh + (size_t)l * GATES * HID,
            g_hh + l * GATES, b_hh + l * GATES,
            g_c + l * HID, b_c + l * HID,
            P, hHi, hMid, hLo, zbuf, flagsA, flagsB,
            shi[l], slo[l],
            tail + l * BATCH * HID,
            tail + 2 * BATCH * HID + l * BATCH * HID);
    }

    f32_split_k<<<16000, 256, 0, stream>>>(W_fc, WfcHi, nullptr, VOCAB * HID / 4);
    gemm_split<1><<<dim3(VOCAB / 128, NROWS / 128), 256, 0, stream>>>(
        hseq1Hi, nullptr, WfcHi, nullptr, b_fc, out, NROWS, VOCAB);
    logsoftmax_k<<<NROWS, 512, 0, stream>>>(out);
}